// Round 3
// baseline (402.637 us; speedup 1.0000x reference)
//
#include <hip/hip_runtime.h>
#include <math.h>

#define MF 16384
#define HALF 8192
#define PH(i) ((i) ^ (((i) >> 6) & 15))

__device__ __forceinline__ float2 cmul(float2 a, float2 b){ return make_float2(a.x*b.x - a.y*b.y, a.x*b.y + a.y*b.x); }
__device__ __forceinline__ float2 cmulc(float2 a, float2 b){ return make_float2(a.x*b.x + a.y*b.y, a.y*b.x - a.x*b.y); } // a*conj(b)
__device__ __forceinline__ int rho4(int v){ return ((v & 3) << 2) | (v >> 2); }
__device__ __forceinline__ int sob(int k){  // slot of bin
    return (rho4(k & 15) << 10) | (rho4((k >> 4) & 15) << 6) | (rho4((k >> 8) & 15) << 2) | (k >> 12);
}

__device__ __forceinline__ void bf4f(float2&a,float2&b,float2&c,float2&d){
    float t0x=a.x+c.x, t0y=a.y+c.y, t2x=a.x-c.x, t2y=a.y-c.y;
    float t1x=b.x+d.x, t1y=b.y+d.y, t3x=b.x-d.x, t3y=b.y-d.y;
    a=make_float2(t0x+t1x,t0y+t1y);
    b=make_float2(t2x+t3y,t2y-t3x);
    c=make_float2(t0x-t1x,t0y-t1y);
    d=make_float2(t2x-t3y,t2y+t3x);
}
__device__ __forceinline__ void bf4i(float2&a,float2&b,float2&c,float2&d){
    float t0x=a.x+c.x, t0y=a.y+c.y, t2x=a.x-c.x, t2y=a.y-c.y;
    float t1x=b.x+d.x, t1y=b.y+d.y, t3x=b.x-d.x, t3y=b.y-d.y;
    a=make_float2(t0x+t1x,t0y+t1y);
    b=make_float2(t2x-t3y,t2y+t3x);
    c=make_float2(t0x-t1x,t0y-t1y);
    d=make_float2(t2x+t3y,t2y-t3x);
}

#define W16_1 make_float2(0.92387953251128674f, -0.38268343236508978f)
#define W16_2 make_float2(0.70710678118654752f, -0.70710678118654752f)
#define W16_3 make_float2(0.38268343236508978f, -0.92387953251128674f)
#define W16_6 make_float2(-0.70710678118654752f, -0.70710678118654752f)
#define W16_9 make_float2(-0.92387953251128674f, 0.38268343236508978f)

// DFT16, DIF radix-4^2, output digit-reversed: out[j] = X[rho4(j)]
__device__ __forceinline__ void dft16_fwd(float2* x){
    bf4f(x[0],x[4],x[8],x[12]);
    bf4f(x[1],x[5],x[9],x[13]);
    bf4f(x[2],x[6],x[10],x[14]);
    bf4f(x[3],x[7],x[11],x[15]);
    x[5]=cmul(x[5],W16_1);  x[9]=cmul(x[9],W16_2);   x[13]=cmul(x[13],W16_3);
    x[6]=cmul(x[6],W16_2);  { float2 t=x[10]; x[10]=make_float2(t.y,-t.x); } x[14]=cmul(x[14],W16_6);
    x[7]=cmul(x[7],W16_3);  x[11]=cmul(x[11],W16_6); x[15]=cmul(x[15],W16_9);
    bf4f(x[0],x[1],x[2],x[3]);
    bf4f(x[4],x[5],x[6],x[7]);
    bf4f(x[8],x[9],x[10],x[11]);
    bf4f(x[12],x[13],x[14],x[15]);
}
// exact inverse of dft16_fwd, unscaled (result x16)
__device__ __forceinline__ void dft16_inv(float2* x){
    bf4i(x[0],x[1],x[2],x[3]);
    bf4i(x[4],x[5],x[6],x[7]);
    bf4i(x[8],x[9],x[10],x[11]);
    bf4i(x[12],x[13],x[14],x[15]);
    x[5]=cmulc(x[5],W16_1); x[9]=cmulc(x[9],W16_2);  x[13]=cmulc(x[13],W16_3);
    x[6]=cmulc(x[6],W16_2); { float2 t=x[10]; x[10]=make_float2(-t.y,t.x); } x[14]=cmulc(x[14],W16_6);
    x[7]=cmulc(x[7],W16_3); x[11]=cmulc(x[11],W16_6); x[15]=cmulc(x[15],W16_9);
    bf4i(x[0],x[4],x[8],x[12]);
    bf4i(x[1],x[5],x[9],x[13]);
    bf4i(x[2],x[6],x[10],x[14]);
    bf4i(x[3],x[7],x[11],x[15]);
}

// ---- forward: natural -> slot order; caller barriers before entry; trailing barrier inside ----
__device__ __forceinline__ void fwd_passes(float2* A, const float2* __restrict__ tw0,
                                           const float2* __restrict__ tw1, const float2* __restrict__ tw2, int tid){
    float2 x[16];
    { // P0: e = tid + (m<<10); sigma const per thread
        int base = PH(tid);
        #pragma unroll
        for(int m=0;m<16;++m) x[m] = A[base + (m<<10)];
        dft16_fwd(x);
        #pragma unroll
        for(int j=1;j<16;++j) x[j] = cmul(x[j], tw0[(j<<10)+tid]);
        #pragma unroll
        for(int m=0;m<16;++m) A[base + (m<<10)] = x[m];
    }
    __syncthreads();
    { // P1: e = (tid>>6)*1024 + (tid&63) + 64m; sigma = m
        int i1 = tid & 63;
        int base = ((tid>>6)<<10) | i1;
        #pragma unroll
        for(int m=0;m<16;++m) x[m] = A[(base + (m<<6)) ^ m];
        dft16_fwd(x);
        #pragma unroll
        for(int j=1;j<16;++j) x[j] = cmul(x[j], tw1[(j<<6)+i1]);
        #pragma unroll
        for(int m=0;m<16;++m) A[(base + (m<<6)) ^ m] = x[m];
    }
    __syncthreads();
    { // P2: e = (tid>>2)*64 + (tid&3) + 4m; sigma = (tid>>2)&15
        int b = tid>>2, j2 = tid&3;
        int base = (b<<6) | j2;
        int sg = b & 15;
        #pragma unroll
        for(int m=0;m<16;++m) x[m] = A[(base + (m<<2)) ^ sg];
        dft16_fwd(x);
        #pragma unroll
        for(int j=1;j<16;++j) x[j] = cmul(x[j], tw2[(j<<2)+j2]);
        #pragma unroll
        for(int m=0;m<16;++m) A[(base + (m<<2)) ^ sg] = x[m];
    }
    __syncthreads();
    { // P3: plain radix-4, 4 butterflies/thread; sigma = (tid>>4)&15
        int sg = (tid>>4) & 15;
        #pragma unroll
        for(int rr=0; rr<4; ++rr){
            int base = (tid<<2) + (rr<<12);
            float2 a=A[(base+0)^sg], b=A[(base+1)^sg], c=A[(base+2)^sg], d=A[(base+3)^sg];
            bf4f(a,b,c,d);
            A[(base+0)^sg]=a; A[(base+1)^sg]=b; A[(base+2)^sg]=c; A[(base+3)^sg]=d;
        }
    }
    __syncthreads();
}

// ---- inverse: slot order -> natural, unscaled (x MF); trailing barrier inside ----
__device__ __forceinline__ void inv_passes(float2* A, const float2* __restrict__ tw0,
                                           const float2* __restrict__ tw1, const float2* __restrict__ tw2, int tid){
    float2 x[16];
    { // IP3
        int sg = (tid>>4) & 15;
        #pragma unroll
        for(int rr=0; rr<4; ++rr){
            int base = (tid<<2) + (rr<<12);
            float2 a=A[(base+0)^sg], b=A[(base+1)^sg], c=A[(base+2)^sg], d=A[(base+3)^sg];
            bf4i(a,b,c,d);
            A[(base+0)^sg]=a; A[(base+1)^sg]=b; A[(base+2)^sg]=c; A[(base+3)^sg]=d;
        }
    }
    __syncthreads();
    { // IP2
        int b = tid>>2, j2 = tid&3;
        int base = (b<<6) | j2;
        int sg = b & 15;
        #pragma unroll
        for(int m=0;m<16;++m) x[m] = A[(base + (m<<2)) ^ sg];
        #pragma unroll
        for(int j=1;j<16;++j) x[j] = cmulc(x[j], tw2[(j<<2)+j2]);
        dft16_inv(x);
        #pragma unroll
        for(int m=0;m<16;++m) A[(base + (m<<2)) ^ sg] = x[m];
    }
    __syncthreads();
    { // IP1
        int i1 = tid & 63;
        int base = ((tid>>6)<<10) | i1;
        #pragma unroll
        for(int m=0;m<16;++m) x[m] = A[(base + (m<<6)) ^ m];
        #pragma unroll
        for(int j=1;j<16;++j) x[j] = cmulc(x[j], tw1[(j<<6)+i1]);
        dft16_inv(x);
        #pragma unroll
        for(int m=0;m<16;++m) A[(base + (m<<6)) ^ m] = x[m];
    }
    __syncthreads();
    { // IP0
        int base = PH(tid);
        #pragma unroll
        for(int m=0;m<16;++m) x[m] = A[base + (m<<10)];
        #pragma unroll
        for(int j=1;j<16;++j) x[j] = cmulc(x[j], tw0[(j<<10)+tid]);
        dft16_inv(x);
        #pragma unroll
        for(int m=0;m<16;++m) A[base + (m<<10)] = x[m];
    }
    __syncthreads();
}

// ---------------- init: all twiddle/unpack tables ----------------
__global__ void k_init(float2* __restrict__ tw0, float2* __restrict__ tw1,
                       float2* __restrict__ tw2, float4* __restrict__ upk) {
    int id = blockIdx.x * 256 + threadIdx.x;
    const double TP = 6.2831853071795864769;
    if (id < 16384) {
        int j = id >> 10, i = id & 1023;
        double a = -TP * (double)(i * rho4(j)) / 16384.0;
        tw0[id] = make_float2((float)cos(a), (float)sin(a));
    } else if (id < 16384 + 1024) {
        int q = id - 16384; int j = q >> 6, i1 = q & 63;
        double a = -TP * (double)(i1 * rho4(j)) / 1024.0;
        tw1[q] = make_float2((float)cos(a), (float)sin(a));
    } else if (id < 16384 + 1024 + 64) {
        int q = id - 16384 - 1024; int j = q >> 2, i2 = q & 3;
        double a = -TP * (double)(i2 * rho4(j)) / 64.0;
        tw2[q] = make_float2((float)cos(a), (float)sin(a));
    } else if (id < 16384 + 1024 + 64 + 16384) {
        int s = id - (16384 + 1024 + 64);
        int k = rho4(s >> 10) | (rho4((s >> 6) & 15) << 4) | (rho4((s >> 2) & 15) << 8) | ((s & 3) << 12);
        double a = -TP * 0.5 * (double)k / 16384.0;   // exp(-i*pi*k/MF)
        int kp = (16384 - k) & 16383;
        upk[s] = make_float4((float)cos(a), (float)sin(a), __int_as_float(sob(kp)), 0.f);
    }
}

// ---------------- evaluate generating function (f32, stable form), E[d][l] ----------------
__global__ __launch_bounds__(1024) void k_eval(const float2* __restrict__ Lam, const float2* __restrict__ P,
                                               const float2* __restrict__ Bc, const float2* __restrict__ C,
                                               const float* __restrict__ log_step, float2* __restrict__ E) {
    __shared__ float2 bTs[16][64];
    __shared__ float2 pTs[16][64];
    __shared__ float2 S10s[16], S11s[16];
    __shared__ float2 C_l[64][65];
    __shared__ float2 tile[16][65];
    int tid = threadIdx.x;
    int l0 = blockIdx.x * 64;
    float step = expf(log_step[0]);
    {
        int dq = tid >> 6, n = tid & 63;
        #pragma unroll
        for (int p = 0; p < 4; ++p) { int dd = dq + p * 16; C_l[n][dd] = C[dd * 64 + n]; }
    }
    __syncthreads();
    int w = tid >> 6;
    int lane = tid & 63;
    for (int p = 0; p < 4; ++p) {
        int l = l0 + p * 16 + w;
        float lf = (float)l * (1.0f / 16384.0f);
        float s2 = sinpif(lf), c2 = cospif(lf);
        float2 q1 = make_float2(2.0f*c2*c2, -2.0f*s2*c2);   // 1+Om
        {
            int n = lane;
            float2 q2 = make_float2(4.0f*s2*s2, 4.0f*s2*c2); // 2(1-Om)
            float2 ln = Lam[n];
            float2 lq = cmul(ln, q1);
            float2 den = make_float2(q2.x - step*lq.x, q2.y - step*lq.y);
            float idn = step / (den.x*den.x + den.y*den.y);
            float2 T = make_float2(den.x*idn, -den.y*idn);
            float2 bn = Bc[n], pn = P[n];
            float2 bT = cmul(bn, T), pT = cmul(pn, T);
            bTs[w][n] = bT; pTs[w][n] = pT;
            float2 s10 = make_float2(pn.x*bT.x + pn.y*bT.y, pn.x*bT.y - pn.y*bT.x);
            float2 s11 = make_float2(pn.x*pT.x + pn.y*pT.y, pn.x*pT.y - pn.y*pT.x);
            #pragma unroll
            for (int off = 32; off > 0; off >>= 1) {
                s10.x += __shfl_xor(s10.x, off);
                s10.y += __shfl_xor(s10.y, off);
                s11.x += __shfl_xor(s11.x, off);
                s11.y += __shfl_xor(s11.y, off);
            }
            if (n == 0) { S10s[w] = s10; S11s[w] = s11; }
        }
        __syncthreads();
        {
            int d = lane;
            float2 S00 = make_float2(0.f, 0.f), S01 = make_float2(0.f, 0.f);
            #pragma unroll 8
            for (int n = 0; n < 64; ++n) {
                float2 cn = C_l[n][d];
                float2 bT = bTs[w][n];
                float2 pT = pTs[w][n];
                S00.x += cn.x*bT.x + cn.y*bT.y;  S00.y += cn.x*bT.y - cn.y*bT.x;
                S01.x += cn.x*pT.x + cn.y*pT.y;  S01.y += cn.x*pT.y - cn.y*pT.x;
            }
            float2 S10 = S10s[w], S11 = S11s[w];
            float2 k11 = cmul(q1, S11); k11.x += 1.0f;
            float2 k10q = cmul(q1, S10);
            float ik = 1.0f / (k11.x*k11.x + k11.y*k11.y);
            float2 quo = make_float2((k10q.x*k11.x + k10q.y*k11.y) * ik,
                                     (k10q.y*k11.x - k10q.x*k11.y) * ik);
            float2 corr = cmul(S01, quo);
            tile[w][d] = make_float2(2.0f*(S00.x - corr.x), 2.0f*(S00.y - corr.y));
        }
        __syncthreads();
        {
            int lo = tid & 15, dq = tid >> 4;
            E[(size_t)dq * MF + l0 + p * 16 + lo] = tile[lo][dq];
        }
        __syncthreads();
    }
}

// ---------------- prep: E -> (inv FFT) -> K -> (pack, fwd FFT) -> Ktab[d][s] = (KdA, KdB) ----------------
__global__ __launch_bounds__(1024) void k_prep(const float2* __restrict__ E, float4* __restrict__ Ktab,
                                               const float2* __restrict__ tw0, const float2* __restrict__ tw1,
                                               const float2* __restrict__ tw2, const float4* __restrict__ upk) {
    __shared__ float2 A[MF];
    int d = blockIdx.x, tid = threadIdx.x;
    const float2* Ed = E + (size_t)d * MF;
    #pragma unroll
    for (int r = 0; r < 16; ++r) { int l = tid + (r << 10); A[PH(sob(l))] = Ed[l]; }
    __syncthreads();
    inv_passes(A, tw0, tw1, tw2, tid);
    // repack: z[t] = (K[2t], K[2t+1]) / MF for t<HALF, else 0
    const float s = 1.0f / (float)MF;
    float2 rv[8];
    #pragma unroll
    for (int r = 0; r < 8; ++r) {
        int t = tid + (r << 10);
        rv[r] = make_float2(A[PH(2*t)].x * s, A[PH(2*t+1)].x * s);
    }
    __syncthreads();
    #pragma unroll
    for (int r = 0; r < 16; ++r) {
        int t = tid + (r << 10);
        A[PH(t)] = (r < 8) ? rv[r] : make_float2(0.f, 0.f);
    }
    __syncthreads();
    fwd_passes(A, tw0, tw1, tw2, tid);
    float4* Kd = Ktab + (size_t)d * MF;
    #pragma unroll
    for (int r = 0; r < 16; ++r) {
        int sl = tid + (r << 10);
        float4 uw = upk[sl];
        int p = __float_as_int(uw.z);
        float2 w = make_float2(uw.x, uw.y);
        float2 Zk = A[PH(sl)];
        float2 Zm = A[PH(p)]; Zm.y = -Zm.y;
        float2 Ue = make_float2(0.5f*(Zk.x + Zm.x), 0.5f*(Zk.y + Zm.y));
        float2 dd = make_float2(Zk.x - Zm.x, Zk.y - Zm.y);
        float2 Uo = make_float2(0.5f*dd.y, -0.5f*dd.x);
        float2 t2 = cmul(w, Uo);
        Kd[sl] = make_float4(Ue.x + t2.x, Ue.y + t2.y, Ue.x - t2.x, Ue.y - t2.y);
    }
}

// ---------------- transpose u (B,L,D) -> uT (B,D,L) ----------------
__global__ void k_transpose_in(const float* __restrict__ u, float* __restrict__ uT) {
    __shared__ float tile[64][65];
    int b = blockIdx.y, t0 = blockIdx.x * 64, tid = threadIdx.x;
    #pragma unroll
    for (int k2 = 0; k2 < 16; ++k2) {
        int idx = tid + k2 * 256;
        int tl = idx >> 6, dl = idx & 63;
        tile[tl][dl] = u[((size_t)(b * MF + t0 + tl)) * 64 + dl];
    }
    __syncthreads();
    #pragma unroll
    for (int k2 = 0; k2 < 16; ++k2) {
        int idx = tid + k2 * 256;
        int dl = idx >> 6, tl = idx & 63;
        uT[((size_t)b * 64 + dl) * MF + t0 + tl] = tile[tl][dl];
    }
}

// ---------------- main conv ----------------
template<bool TRANS>
__global__ __launch_bounds__(1024) void k_conv(const float* __restrict__ u, const float* __restrict__ uT,
                                               const float4* __restrict__ Ktab, const float* __restrict__ Dp,
                                               float* __restrict__ yT, float* __restrict__ yout,
                                               const float2* __restrict__ tw0, const float2* __restrict__ tw1,
                                               const float2* __restrict__ tw2, const float4* __restrict__ upk) {
    __shared__ float2 A[MF];
    int bd = blockIdx.x, tid = threadIdx.x;
    int b = bd >> 6, d = bd & 63;
    if (TRANS) {
        const float2* src = (const float2*)(uT + (size_t)bd * MF);
        #pragma unroll
        for (int r = 0; r < 16; ++r) {
            int t = tid + (r << 10);
            A[PH(t)] = (t < HALF) ? src[t] : make_float2(0.f, 0.f);
        }
    } else {
        const float* ub = u + ((size_t)b * MF) * 64 + d;
        #pragma unroll
        for (int r = 0; r < 16; ++r) {
            int t = tid + (r << 10);
            float2 v = make_float2(0.f, 0.f);
            if (t < HALF) { v.x = ub[(size_t)(2 * t) * 64]; v.y = ub[(size_t)(2 * t + 1) * 64]; }
            A[PH(t)] = v;
        }
    }
    __syncthreads();
    fwd_passes(A, tw0, tw1, tw2, tid);
    const float4* Kd = Ktab + (size_t)d * MF;
    float2 Wr[16];
    #pragma unroll
    for (int r = 0; r < 16; ++r) {
        int sl = tid + (r << 10);
        float4 uw = upk[sl];
        int p = __float_as_int(uw.z);
        float2 w = make_float2(uw.x, uw.y);
        float2 Zk = A[PH(sl)];
        float2 Zm = A[PH(p)]; Zm.y = -Zm.y;
        float2 Ue = make_float2(0.5f*(Zk.x + Zm.x), 0.5f*(Zk.y + Zm.y));
        float2 dd = make_float2(Zk.x - Zm.x, Zk.y - Zm.y);
        float2 Uo = make_float2(0.5f*dd.y, -0.5f*dd.x);
        float2 t2 = cmul(w, Uo);
        float2 X0 = make_float2(Ue.x + t2.x, Ue.y + t2.y);
        float2 X1 = make_float2(Ue.x - t2.x, Ue.y - t2.y);
        float4 kd = Kd[sl];
        float2 Y0 = cmul(X0, make_float2(kd.x, kd.y));
        float2 Y1 = cmul(X1, make_float2(kd.z, kd.w));
        float2 Ey = make_float2(0.5f*(Y0.x + Y1.x), 0.5f*(Y0.y + Y1.y));
        float2 Dy = make_float2(Y0.x - Y1.x, Y0.y - Y1.y);
        float2 Oy = cmulc(Dy, w);
        Oy.x *= 0.5f; Oy.y *= 0.5f;
        Wr[r] = make_float2(Ey.x - Oy.y, Ey.y + Oy.x);   // Z' = Ey + i*Oy
    }
    __syncthreads();
    #pragma unroll
    for (int r = 0; r < 16; ++r) { int sl = tid + (r << 10); A[PH(sl)] = Wr[r]; }
    __syncthreads();
    inv_passes(A, tw0, tw1, tw2, tid);
    const float sc = 1.0f / (float)MF;
    if (TRANS) {
        float2* dst = (float2*)(yT + (size_t)bd * MF);
        #pragma unroll
        for (int r = 0; r < 8; ++r) {
            int t = tid + (r << 10);
            float2 v = A[PH(t)];
            dst[t] = make_float2(v.x * sc, v.y * sc);
        }
    } else {
        float Dd = Dp[d];
        float* yb = yout + ((size_t)b * MF) * 64 + d;
        const float* ub = u + ((size_t)b * MF) * 64 + d;
        #pragma unroll
        for (int r = 0; r < 8; ++r) {
            int t = tid + (r << 10);
            float2 v = A[PH(t)];
            yb[(size_t)(2 * t) * 64]     = v.x * sc + Dd * ub[(size_t)(2 * t) * 64];
            yb[(size_t)(2 * t + 1) * 64] = v.y * sc + Dd * ub[(size_t)(2 * t + 1) * 64];
        }
    }
}

// ---------------- output: y[b][t][d] = yT[b][d][t] + D[d]*u[b][t][d] ----------------
__global__ void k_out(const float* __restrict__ yT, const float* __restrict__ u,
                      const float* __restrict__ Dp, float* __restrict__ y) {
    __shared__ float tile[64][65];
    int b = blockIdx.y, t0 = blockIdx.x * 64, tid = threadIdx.x;
    #pragma unroll
    for (int k2 = 0; k2 < 16; ++k2) {
        int idx = tid + k2 * 256;
        int dl = idx >> 6, tl = idx & 63;
        tile[dl][tl] = yT[((size_t)b * 64 + dl) * MF + t0 + tl];
    }
    __syncthreads();
    #pragma unroll
    for (int k2 = 0; k2 < 16; ++k2) {
        int idx = tid + k2 * 256;
        int tl = idx >> 6, dl = idx & 63;
        size_t gi = ((size_t)(b * MF + t0 + tl)) * 64 + dl;
        y[gi] = tile[dl][tl] + Dp[dl] * u[gi];
    }
}

extern "C" void kernel_launch(void* const* d_in, const int* in_sizes, int n_in,
                              void* d_out, int out_size, void* d_ws, size_t ws_size,
                              hipStream_t stream) {
    const float*  u   = (const float*)d_in[0];
    const float2* Lam = (const float2*)d_in[1];
    const float2* P   = (const float2*)d_in[2];
    const float2* Bc  = (const float2*)d_in[3];
    const float2* C   = (const float2*)d_in[4];
    const float*  Dp  = (const float*)d_in[5];
    const float*  ls  = (const float*)d_in[6];
    float* y = (float*)d_out;
    char* ws = (char*)d_ws;

    size_t off = 0;
    float2* tw0 = (float2*)(ws + off); off += (size_t)16384 * sizeof(float2);        // 128 KB
    float2* tw1 = (float2*)(ws + off); off += (size_t)1024 * sizeof(float2);         // 8 KB
    float2* tw2 = (float2*)(ws + off); off += (size_t)64 * sizeof(float2) + 512;     // pad to 16B/alignment slack
    float4* upk = (float4*)(ws + off); off += (size_t)16384 * sizeof(float4);        // 256 KB
    float2* E   = (float2*)(ws + off); off += (size_t)64 * MF * sizeof(float2);      // 8 MB
    float4* Ktab= (float4*)(ws + off); off += (size_t)64 * MF * sizeof(float4);      // 16 MB
    float*  uT  = (float*) (ws + off); off += (size_t)1024 * MF * sizeof(float);     // 64 MB
    float*  yT  = (float*) (ws + off); off += (size_t)1024 * MF * sizeof(float);     // 64 MB
    bool trans = (ws_size >= off);

    k_init<<<(16384 + 1024 + 64 + 16384 + 255) / 256, 256, 0, stream>>>(tw0, tw1, tw2, upk);
    k_eval<<<256, 1024, 0, stream>>>(Lam, P, Bc, C, ls, E);
    k_prep<<<64, 1024, 0, stream>>>(E, Ktab, tw0, tw1, tw2, upk);

    if (trans) {
        dim3 tg(MF / 64, 16);
        k_transpose_in<<<tg, 256, 0, stream>>>(u, uT);
        k_conv<true><<<1024, 1024, 0, stream>>>(u, uT, Ktab, Dp, yT, y, tw0, tw1, tw2, upk);
        k_out<<<tg, 256, 0, stream>>>(yT, u, Dp, y);
    } else {
        k_conv<false><<<1024, 1024, 0, stream>>>(u, nullptr, Ktab, Dp, nullptr, y, tw0, tw1, tw2, upk);
    }
}

// Round 4
// 291.136 us; speedup vs baseline: 1.3830x; 1.3830x over previous
//
#include <hip/hip_runtime.h>
#include <math.h>

#define MF 16384
#define HALF 8192

__device__ __forceinline__ float2 cmul(float2 a, float2 b){ return make_float2(a.x*b.x - a.y*b.y, a.x*b.y + a.y*b.x); }
__device__ __forceinline__ float2 cmulc(float2 a, float2 b){ return make_float2(a.x*b.x + a.y*b.y, a.y*b.x - a.x*b.y); } // a*conj(b)
__device__ __forceinline__ int rho4(int v){ return ((v & 3) << 2) | (v >> 2); }
__device__ __forceinline__ int sob(int k){  // slot of bin
    return (rho4(k & 15) << 10) | (rho4((k >> 4) & 15) << 6) | (rho4((k >> 8) & 15) << 2) | (k >> 12);
}
// physical LDS slot: spreads low-4 addr bits within every 16-lane group for all pass geometries
__device__ __forceinline__ int ph(int e){ return e ^ ((e >> 4) & 3) ^ (((e >> 6) & 3) << 2); }

__device__ __forceinline__ void bf4f(float2&a,float2&b,float2&c,float2&d){
    float t0x=a.x+c.x, t0y=a.y+c.y, t2x=a.x-c.x, t2y=a.y-c.y;
    float t1x=b.x+d.x, t1y=b.y+d.y, t3x=b.x-d.x, t3y=b.y-d.y;
    a=make_float2(t0x+t1x,t0y+t1y);
    b=make_float2(t2x+t3y,t2y-t3x);
    c=make_float2(t0x-t1x,t0y-t1y);
    d=make_float2(t2x-t3y,t2y+t3x);
}
__device__ __forceinline__ void bf4i(float2&a,float2&b,float2&c,float2&d){
    float t0x=a.x+c.x, t0y=a.y+c.y, t2x=a.x-c.x, t2y=a.y-c.y;
    float t1x=b.x+d.x, t1y=b.y+d.y, t3x=b.x-d.x, t3y=b.y-d.y;
    a=make_float2(t0x+t1x,t0y+t1y);
    b=make_float2(t2x-t3y,t2y+t3x);
    c=make_float2(t0x-t1x,t0y-t1y);
    d=make_float2(t2x+t3y,t2y-t3x);
}

#define W16_1 make_float2(0.92387953251128674f, -0.38268343236508978f)
#define W16_2 make_float2(0.70710678118654752f, -0.70710678118654752f)
#define W16_3 make_float2(0.38268343236508978f, -0.92387953251128674f)
#define W16_6 make_float2(-0.70710678118654752f, -0.70710678118654752f)
#define W16_9 make_float2(-0.92387953251128674f, 0.38268343236508978f)

__device__ __forceinline__ void dft16_fwd(float2* x){
    bf4f(x[0],x[4],x[8],x[12]);
    bf4f(x[1],x[5],x[9],x[13]);
    bf4f(x[2],x[6],x[10],x[14]);
    bf4f(x[3],x[7],x[11],x[15]);
    x[5]=cmul(x[5],W16_1);  x[9]=cmul(x[9],W16_2);   x[13]=cmul(x[13],W16_3);
    x[6]=cmul(x[6],W16_2);  { float2 t=x[10]; x[10]=make_float2(t.y,-t.x); } x[14]=cmul(x[14],W16_6);
    x[7]=cmul(x[7],W16_3);  x[11]=cmul(x[11],W16_6); x[15]=cmul(x[15],W16_9);
    bf4f(x[0],x[1],x[2],x[3]);
    bf4f(x[4],x[5],x[6],x[7]);
    bf4f(x[8],x[9],x[10],x[11]);
    bf4f(x[12],x[13],x[14],x[15]);
}
__device__ __forceinline__ void dft16_inv(float2* x){
    bf4i(x[0],x[1],x[2],x[3]);
    bf4i(x[4],x[5],x[6],x[7]);
    bf4i(x[8],x[9],x[10],x[11]);
    bf4i(x[12],x[13],x[14],x[15]);
    x[5]=cmulc(x[5],W16_1); x[9]=cmulc(x[9],W16_2);  x[13]=cmulc(x[13],W16_3);
    x[6]=cmulc(x[6],W16_2); { float2 t=x[10]; x[10]=make_float2(-t.y,t.x); } x[14]=cmulc(x[14],W16_6);
    x[7]=cmulc(x[7],W16_3); x[11]=cmulc(x[11],W16_6); x[15]=cmulc(x[15],W16_9);
    bf4i(x[0],x[4],x[8],x[12]);
    bf4i(x[1],x[5],x[9],x[13]);
    bf4i(x[2],x[6],x[10],x[14]);
    bf4i(x[3],x[7],x[11],x[15]);
}

// ---- pass 0: stride-1024 subtransform; twiddles = powers of base[tid] (registers) ----
template<bool INV>
__device__ __forceinline__ void pass0(float2* A, const float2* bas, int tid){
    float2 x[16];
    int base = ph(tid);
    #pragma unroll
    for(int m=0;m<16;++m) x[m] = A[base + (m<<10)];
    float2 w1 = bas[tid];
    float2 w2=cmul(w1,w1), w4=cmul(w2,w2), w8=cmul(w4,w4);
    float2 w3=cmul(w2,w1), w5=cmul(w4,w1), w6=cmul(w4,w2), w7=cmul(w4,w3);
    float2 w9=cmul(w8,w1), w10=cmul(w8,w2), w11=cmul(w8,w3), w12=cmul(w8,w4);
    float2 w13=cmul(w8,w5), w14=cmul(w8,w6), w15=cmul(w8,w7);
    if (!INV){
        dft16_fwd(x);
        x[1]=cmul(x[1],w4);   x[2]=cmul(x[2],w8);   x[3]=cmul(x[3],w12);
        x[4]=cmul(x[4],w1);   x[5]=cmul(x[5],w5);   x[6]=cmul(x[6],w9);
        x[7]=cmul(x[7],w13);  x[8]=cmul(x[8],w2);   x[9]=cmul(x[9],w6);
        x[10]=cmul(x[10],w10);x[11]=cmul(x[11],w14);x[12]=cmul(x[12],w3);
        x[13]=cmul(x[13],w7); x[14]=cmul(x[14],w11);x[15]=cmul(x[15],w15);
    } else {
        x[1]=cmulc(x[1],w4);   x[2]=cmulc(x[2],w8);   x[3]=cmulc(x[3],w12);
        x[4]=cmulc(x[4],w1);   x[5]=cmulc(x[5],w5);   x[6]=cmulc(x[6],w9);
        x[7]=cmulc(x[7],w13);  x[8]=cmulc(x[8],w2);   x[9]=cmulc(x[9],w6);
        x[10]=cmulc(x[10],w10);x[11]=cmulc(x[11],w14);x[12]=cmulc(x[12],w3);
        x[13]=cmulc(x[13],w7); x[14]=cmulc(x[14],w11);x[15]=cmulc(x[15],w15);
        dft16_inv(x);
    }
    #pragma unroll
    for(int m=0;m<16;++m) A[base + (m<<10)] = x[m];
}

// ---- pass 1: stride-64; twiddles from LDS table ----
template<bool INV>
__device__ __forceinline__ void pass1(float2* A, const float2* tw1s, int tid){
    float2 x[16];
    int i1 = tid & 63;
    int B = (tid >> 6) << 10;
    int i1x = i1 ^ ((i1 >> 4) & 3);
    #pragma unroll
    for(int m=0;m<16;++m) x[m] = A[B + (m<<6) + (i1x ^ ((m&3)<<2))];
    if (!INV){
        dft16_fwd(x);
        #pragma unroll
        for(int j=1;j<16;++j) x[j] = cmul(x[j], tw1s[(j<<6)+i1]);
    } else {
        #pragma unroll
        for(int j=1;j<16;++j) x[j] = cmulc(x[j], tw1s[(j<<6)+i1]);
        dft16_inv(x);
    }
    #pragma unroll
    for(int m=0;m<16;++m) A[B + (m<<6) + (i1x ^ ((m&3)<<2))] = x[m];
}

// ---- pass 2: stride-4; twiddles from LDS table (broadcast) ----
template<bool INV>
__device__ __forceinline__ void pass2(float2* A, const float2* tw2s, int tid){
    float2 x[16];
    int q = tid >> 2, j2 = tid & 3;
    int qb = q << 6;
    int qx = (q & 3) << 2;
    #pragma unroll
    for(int m=0;m<16;++m) x[m] = A[qb + ((((m<<2)|j2) ^ ((m>>2)&3)) ^ qx)];
    if (!INV){
        dft16_fwd(x);
        #pragma unroll
        for(int j=1;j<16;++j) x[j] = cmul(x[j], tw2s[(j<<2)+j2]);
    } else {
        #pragma unroll
        for(int j=1;j<16;++j) x[j] = cmulc(x[j], tw2s[(j<<2)+j2]);
        dft16_inv(x);
    }
    #pragma unroll
    for(int m=0;m<16;++m) A[qb + ((((m<<2)|j2) ^ ((m>>2)&3)) ^ qx)] = x[m];
}

// ---- pass 3: final radix-4, no twiddles ----
template<bool INV>
__device__ __forceinline__ void pass3(float2* A, int tid){
    int sgm = ((tid>>2)&3) ^ (((tid>>4)&3)<<2);
    #pragma unroll
    for(int rr=0; rr<4; ++rr){
        int base = (tid<<2) | (rr<<12);
        float2 a=A[(base|0)^sgm], b=A[(base|1)^sgm], c=A[(base|2)^sgm], d=A[(base|3)^sgm];
        if(!INV) bf4f(a,b,c,d); else bf4i(a,b,c,d);
        A[(base|0)^sgm]=a; A[(base|1)^sgm]=b; A[(base|2)^sgm]=c; A[(base|3)^sgm]=d;
    }
}

// ---------------- init: small twiddle tables only ----------------
__global__ void k_init(float2* __restrict__ baseg, float2* __restrict__ tw1g, float2* __restrict__ tw2g){
    int id = blockIdx.x * 256 + threadIdx.x;
    const double TP = 6.2831853071795864769;
    if (id < 1024){
        double a = -TP * (double)id / 16384.0;
        baseg[id] = make_float2((float)cos(a), (float)sin(a));
    } else if (id < 2048){
        int q = id - 1024; int j = q >> 6, i1 = q & 63;
        double a = -TP * (double)(i1 * rho4(j)) / 1024.0;
        tw1g[q] = make_float2((float)cos(a), (float)sin(a));
    } else if (id < 2048 + 64){
        int q = id - 2048; int j = q >> 2, i2 = q & 3;
        double a = -TP * (double)(i2 * rho4(j)) / 64.0;
        tw2g[q] = make_float2((float)cos(a), (float)sin(a));
    }
}

// ---------------- evaluate generating function (f32, stable form), E[d][l] ----------------
__global__ __launch_bounds__(1024) void k_eval(const float2* __restrict__ Lam, const float2* __restrict__ P,
                                               const float2* __restrict__ Bc, const float2* __restrict__ C,
                                               const float* __restrict__ log_step, float2* __restrict__ E) {
    __shared__ float2 bTs[16][64];
    __shared__ float2 pTs[16][64];
    __shared__ float2 S10s[16], S11s[16];
    __shared__ float2 C_l[64][65];
    __shared__ float2 tile[16][65];
    int tid = threadIdx.x;
    int l0 = blockIdx.x * 64;
    float step = expf(log_step[0]);
    {
        int dq = tid >> 6, n = tid & 63;
        #pragma unroll
        for (int p = 0; p < 4; ++p) { int dd = dq + p * 16; C_l[n][dd] = C[dd * 64 + n]; }
    }
    __syncthreads();
    int w = tid >> 6;
    int lane = tid & 63;
    for (int p = 0; p < 4; ++p) {
        int l = l0 + p * 16 + w;
        float lf = (float)l * (1.0f / 16384.0f);
        float s2 = sinpif(lf), c2 = cospif(lf);
        float2 q1 = make_float2(2.0f*c2*c2, -2.0f*s2*c2);   // 1+Om
        {
            int n = lane;
            float2 q2 = make_float2(4.0f*s2*s2, 4.0f*s2*c2); // 2(1-Om)
            float2 ln = Lam[n];
            float2 lq = cmul(ln, q1);
            float2 den = make_float2(q2.x - step*lq.x, q2.y - step*lq.y);
            float idn = step / (den.x*den.x + den.y*den.y);
            float2 T = make_float2(den.x*idn, -den.y*idn);
            float2 bn = Bc[n], pn = P[n];
            float2 bT = cmul(bn, T), pT = cmul(pn, T);
            bTs[w][n] = bT; pTs[w][n] = pT;
            float2 s10 = make_float2(pn.x*bT.x + pn.y*bT.y, pn.x*bT.y - pn.y*bT.x);
            float2 s11 = make_float2(pn.x*pT.x + pn.y*pT.y, pn.x*pT.y - pn.y*pT.x);
            #pragma unroll
            for (int off = 32; off > 0; off >>= 1) {
                s10.x += __shfl_xor(s10.x, off);
                s10.y += __shfl_xor(s10.y, off);
                s11.x += __shfl_xor(s11.x, off);
                s11.y += __shfl_xor(s11.y, off);
            }
            if (n == 0) { S10s[w] = s10; S11s[w] = s11; }
        }
        __syncthreads();
        {
            int d = lane;
            float2 S00 = make_float2(0.f, 0.f), S01 = make_float2(0.f, 0.f);
            #pragma unroll 8
            for (int n = 0; n < 64; ++n) {
                float2 cn = C_l[n][d];
                float2 bT = bTs[w][n];
                float2 pT = pTs[w][n];
                S00.x += cn.x*bT.x + cn.y*bT.y;  S00.y += cn.x*bT.y - cn.y*bT.x;
                S01.x += cn.x*pT.x + cn.y*pT.y;  S01.y += cn.x*pT.y - cn.y*pT.x;
            }
            float2 S10 = S10s[w], S11 = S11s[w];
            float2 k11 = cmul(q1, S11); k11.x += 1.0f;
            float2 k10q = cmul(q1, S10);
            float ik = 1.0f / (k11.x*k11.x + k11.y*k11.y);
            float2 quo = make_float2((k10q.x*k11.x + k10q.y*k11.y) * ik,
                                     (k10q.y*k11.x - k10q.x*k11.y) * ik);
            float2 corr = cmul(S01, quo);
            tile[w][d] = make_float2(2.0f*(S00.x - corr.x), 2.0f*(S00.y - corr.y));
        }
        __syncthreads();
        {
            int lo = tid & 15, dq = tid >> 4;
            E[(size_t)dq * MF + l0 + p * 16 + lo] = tile[lo][dq];
        }
        __syncthreads();
    }
}

// ---------------- prep: E -> ifft -> K -> pack -> fft -> Ktab (slot order, prescaled 1/MF) ----------------
__global__ __launch_bounds__(1024, 4) void k_prep(const float2* __restrict__ E, float4* __restrict__ Ktab,
                                                  const float2* __restrict__ baseg, const float2* __restrict__ tw1g,
                                                  const float2* __restrict__ tw2g) {
    __shared__ float2 A[MF];
    __shared__ float2 bas[1024];
    __shared__ float2 tw1s[1024];
    __shared__ float2 tw2s[64];
    int d = blockIdx.x, tid = threadIdx.x;
    bas[tid] = baseg[tid];
    tw1s[tid] = tw1g[tid];
    if (tid < 64) tw2s[tid] = tw2g[tid];
    const float2* Ed = E + (size_t)d * MF;
    #pragma unroll
    for (int r = 0; r < 16; ++r) { int l = tid + (r << 10); A[ph(sob(l))] = Ed[l]; }
    __syncthreads();
    pass3<true>(A, tid); __syncthreads();
    pass2<true>(A, tw2s, tid); __syncthreads();
    pass1<true>(A, tw1s, tid); __syncthreads();
    pass0<true>(A, bas, tid); __syncthreads();
    const float s = 1.0f / (float)MF;
    float2 rv[8];
    #pragma unroll
    for (int r = 0; r < 8; ++r) {
        int t = tid + (r << 10);
        rv[r] = make_float2(A[ph(2*t)].x * s, A[ph(2*t+1)].x * s);
    }
    __syncthreads();
    int pht = ph(tid);
    #pragma unroll
    for (int r = 0; r < 16; ++r) A[pht + (r << 10)] = (r < 8) ? rv[r] : make_float2(0.f, 0.f);
    __syncthreads();
    pass0<false>(A, bas, tid); __syncthreads();
    pass1<false>(A, tw1s, tid); __syncthreads();
    pass2<false>(A, tw2s, tid); __syncthreads();
    pass3<false>(A, tid); __syncthreads();
    float4* Kd = Ktab + (size_t)d * MF;
    int Cbits = (rho4(tid >> 6) << 4) | (rho4((tid >> 2) & 15) << 8) | ((tid & 3) << 12);
    const float ksc = 1.0f / (float)MF;
    #pragma unroll
    for (int r = 0; r < 16; ++r) {
        int k = Cbits | rho4(r);
        int kp = (MF - k) & (MF - 1);
        int p = sob(kp);
        float kf = (float)k * (1.0f / 16384.0f);
        float2 w = make_float2(cospif(kf), -sinpif(kf));
        float2 Zk = A[pht + (r << 10)];
        float2 Zm = A[ph(p)]; Zm.y = -Zm.y;
        float2 Ue = make_float2(0.5f*(Zk.x + Zm.x), 0.5f*(Zk.y + Zm.y));
        float2 dd = make_float2(Zk.x - Zm.x, Zk.y - Zm.y);
        float2 Uo = make_float2(0.5f*dd.y, -0.5f*dd.x);
        float2 t2 = cmul(w, Uo);
        Kd[tid + (r << 10)] = make_float4((Ue.x + t2.x)*ksc, (Ue.y + t2.y)*ksc,
                                          (Ue.x - t2.x)*ksc, (Ue.y - t2.y)*ksc);
    }
}

// ---------------- transpose u (B,L,D) -> uT (B,D,L) ----------------
__global__ void k_transpose_in(const float* __restrict__ u, float* __restrict__ uT) {
    __shared__ float tile[64][65];
    int b = blockIdx.y, t0 = blockIdx.x * 64, tid = threadIdx.x;
    #pragma unroll
    for (int k2 = 0; k2 < 16; ++k2) {
        int idx = tid + k2 * 256;
        int tl = idx >> 6, dl = idx & 63;
        tile[tl][dl] = u[((size_t)(b * MF + t0 + tl)) * 64 + dl];
    }
    __syncthreads();
    #pragma unroll
    for (int k2 = 0; k2 < 16; ++k2) {
        int idx = tid + k2 * 256;
        int dl = idx >> 6, tl = idx & 63;
        uT[((size_t)b * 64 + dl) * MF + t0 + tl] = tile[tl][dl];
    }
}

// ---------------- main conv ----------------
template<bool TRANS>
__global__ __launch_bounds__(1024, 4) void k_conv(const float* __restrict__ u, const float* __restrict__ uT,
                                                  const float4* __restrict__ Ktab, const float* __restrict__ Dp,
                                                  float* __restrict__ yT, float* __restrict__ yout,
                                                  const float2* __restrict__ baseg, const float2* __restrict__ tw1g,
                                                  const float2* __restrict__ tw2g) {
    __shared__ float2 A[MF];
    __shared__ float2 bas[1024];
    __shared__ float2 tw1s[1024];
    __shared__ float2 tw2s[64];
    int tid = threadIdx.x;
    bas[tid] = baseg[tid];
    tw1s[tid] = tw1g[tid];
    if (tid < 64) tw2s[tid] = tw2g[tid];
    // XCD-chunked swizzle: d-major so each XCD's L2 keeps ~2 Ktab slices hot
    int bid = blockIdx.x;
    int vb = ((bid & 7) << 7) | (bid >> 3);
    int d = vb >> 4, b = vb & 15;
    int bd = (b << 6) | d;
    int pht = ph(tid);
    if (TRANS) {
        const float2* src = (const float2*)(uT + (size_t)bd * MF);
        #pragma unroll
        for (int r = 0; r < 16; ++r) {
            int t = tid + (r << 10);
            A[pht + (r << 10)] = (r < 8) ? src[t] : make_float2(0.f, 0.f);
        }
    } else {
        const float* ub = u + ((size_t)b * MF) * 64 + d;
        #pragma unroll
        for (int r = 0; r < 16; ++r) {
            int t = tid + (r << 10);
            float2 v = make_float2(0.f, 0.f);
            if (r < 8) { v.x = ub[(size_t)(2 * t) * 64]; v.y = ub[(size_t)(2 * t + 1) * 64]; }
            A[pht + (r << 10)] = v;
        }
    }
    __syncthreads();
    pass0<false>(A, bas, tid); __syncthreads();
    pass1<false>(A, tw1s, tid); __syncthreads();
    pass2<false>(A, tw2s, tid); __syncthreads();
    // prefetch Ktab slice into registers (hides L2 latency under pass3)
    const float4* Kd = Ktab + (size_t)d * MF;
    float4 kd[16];
    #pragma unroll
    for (int r = 0; r < 16; ++r) kd[r] = Kd[tid + (r << 10)];
    pass3<false>(A, tid); __syncthreads();
    // pointwise: unpack real-FFT pair, multiply, repack
    int Cbits = (rho4(tid >> 6) << 4) | (rho4((tid >> 2) & 15) << 8) | ((tid & 3) << 12);
    float2 Wr[16];
    #pragma unroll
    for (int r = 0; r < 16; ++r) {
        int k = Cbits | rho4(r);
        int kp = (MF - k) & (MF - 1);
        int p = sob(kp);
        float kf = (float)k * (1.0f / 16384.0f);
        float2 w = make_float2(cospif(kf), -sinpif(kf));
        float2 Zk = A[pht + (r << 10)];
        float2 Zm = A[ph(p)]; Zm.y = -Zm.y;
        float2 Ue = make_float2(0.5f*(Zk.x + Zm.x), 0.5f*(Zk.y + Zm.y));
        float2 dd = make_float2(Zk.x - Zm.x, Zk.y - Zm.y);
        float2 Uo = make_float2(0.5f*dd.y, -0.5f*dd.x);
        float2 t2 = cmul(w, Uo);
        float2 X0 = make_float2(Ue.x + t2.x, Ue.y + t2.y);
        float2 X1 = make_float2(Ue.x - t2.x, Ue.y - t2.y);
        float2 Y0 = cmul(X0, make_float2(kd[r].x, kd[r].y));
        float2 Y1 = cmul(X1, make_float2(kd[r].z, kd[r].w));
        float2 Ey = make_float2(0.5f*(Y0.x + Y1.x), 0.5f*(Y0.y + Y1.y));
        float2 Dy = make_float2(Y0.x - Y1.x, Y0.y - Y1.y);
        float2 Oy = cmulc(Dy, w);
        Oy.x *= 0.5f; Oy.y *= 0.5f;
        Wr[r] = make_float2(Ey.x - Oy.y, Ey.y + Oy.x);   // Z' = Ey + i*Oy
    }
    __syncthreads();
    #pragma unroll
    for (int r = 0; r < 16; ++r) A[pht + (r << 10)] = Wr[r];
    __syncthreads();
    pass3<true>(A, tid); __syncthreads();
    pass2<true>(A, tw2s, tid); __syncthreads();
    pass1<true>(A, tw1s, tid); __syncthreads();
    pass0<true>(A, bas, tid); __syncthreads();
    // store (1/MF already folded into Ktab)
    if (TRANS) {
        float2* dst = (float2*)(yT + (size_t)bd * MF);
        #pragma unroll
        for (int r = 0; r < 8; ++r) dst[tid + (r << 10)] = A[pht + (r << 10)];
    } else {
        float Dd = Dp[d];
        float* yb = yout + ((size_t)b * MF) * 64 + d;
        const float* ub = u + ((size_t)b * MF) * 64 + d;
        #pragma unroll
        for (int r = 0; r < 8; ++r) {
            int t = tid + (r << 10);
            float2 v = A[pht + (r << 10)];
            yb[(size_t)(2 * t) * 64]     = v.x + Dd * ub[(size_t)(2 * t) * 64];
            yb[(size_t)(2 * t + 1) * 64] = v.y + Dd * ub[(size_t)(2 * t + 1) * 64];
        }
    }
}

// ---------------- output: y[b][t][d] = yT[b][d][t] + D[d]*u[b][t][d] ----------------
__global__ void k_out(const float* __restrict__ yT, const float* __restrict__ u,
                      const float* __restrict__ Dp, float* __restrict__ y) {
    __shared__ float tile[64][65];
    int b = blockIdx.y, t0 = blockIdx.x * 64, tid = threadIdx.x;
    #pragma unroll
    for (int k2 = 0; k2 < 16; ++k2) {
        int idx = tid + k2 * 256;
        int dl = idx >> 6, tl = idx & 63;
        tile[dl][tl] = yT[((size_t)b * 64 + dl) * MF + t0 + tl];
    }
    __syncthreads();
    #pragma unroll
    for (int k2 = 0; k2 < 16; ++k2) {
        int idx = tid + k2 * 256;
        int tl = idx >> 6, dl = idx & 63;
        size_t gi = ((size_t)(b * MF + t0 + tl)) * 64 + dl;
        y[gi] = tile[dl][tl] + Dp[dl] * u[gi];
    }
}

extern "C" void kernel_launch(void* const* d_in, const int* in_sizes, int n_in,
                              void* d_out, int out_size, void* d_ws, size_t ws_size,
                              hipStream_t stream) {
    const float*  u   = (const float*)d_in[0];
    const float2* Lam = (const float2*)d_in[1];
    const float2* P   = (const float2*)d_in[2];
    const float2* Bc  = (const float2*)d_in[3];
    const float2* C   = (const float2*)d_in[4];
    const float*  Dp  = (const float*)d_in[5];
    const float*  ls  = (const float*)d_in[6];
    float* y = (float*)d_out;
    char* ws = (char*)d_ws;

    size_t off = 0;
    float2* baseg = (float2*)(ws + off); off += (size_t)1024 * sizeof(float2);        // 8 KB
    float2* tw1g  = (float2*)(ws + off); off += (size_t)1024 * sizeof(float2);        // 8 KB
    float2* tw2g  = (float2*)(ws + off); off += (size_t)64 * sizeof(float2) + 512;    // 1 KB
    float2* E     = (float2*)(ws + off); off += (size_t)64 * MF * sizeof(float2);     // 8 MB
    float4* Ktab  = (float4*)(ws + off); off += (size_t)64 * MF * sizeof(float4);     // 16 MB
    float*  uT    = (float*) (ws + off); off += (size_t)1024 * MF * sizeof(float);    // 64 MB
    float*  yT    = (float*) (ws + off); off += (size_t)1024 * MF * sizeof(float);    // 64 MB
    bool trans = (ws_size >= off);

    k_init<<<9, 256, 0, stream>>>(baseg, tw1g, tw2g);
    k_eval<<<256, 1024, 0, stream>>>(Lam, P, Bc, C, ls, E);
    k_prep<<<64, 1024, 0, stream>>>(E, Ktab, baseg, tw1g, tw2g);

    if (trans) {
        dim3 tg(MF / 64, 16);
        k_transpose_in<<<tg, 256, 0, stream>>>(u, uT);
        k_conv<true><<<1024, 1024, 0, stream>>>(u, uT, Ktab, Dp, yT, y, baseg, tw1g, tw2g);
        k_out<<<tg, 256, 0, stream>>>(yT, u, Dp, y);
    } else {
        k_conv<false><<<1024, 1024, 0, stream>>>(u, nullptr, Ktab, Dp, nullptr, y, baseg, tw1g, tw2g);
    }
}